// Round 2
// 484.663 us; speedup vs baseline: 1.0238x; 1.0238x over previous
//
#include <hip/hip_runtime.h>
#include <hip/hip_bf16.h>
#include <stdint.h>
#include <stddef.h>

// ---------- types ----------
typedef __attribute__((ext_vector_type(8)))  __bf16 bf16x8;   // MFMA A/B frag (4 VGPRs)
typedef __attribute__((ext_vector_type(16))) float  f32x16;   // 32x32 MFMA C/D frag
typedef __attribute__((ext_vector_type(8)))  unsigned short ushort8;

typedef const void __attribute__((address_space(1)))* as1_cvp;
typedef void       __attribute__((address_space(3)))* as3_vp;

__device__ __forceinline__ void gload_lds16(const void* g, void* l) {
    // width=16 -> global_load_lds_dwordx4. LDS dest = wave-uniform base + lane*16.
    __builtin_amdgcn_global_load_lds((as1_cvp)g, (as3_vp)l, 16, 0, 0);
}

__device__ __forceinline__ unsigned short f2bf(float f) {
    union { float f; unsigned u; } v; v.f = f;
    unsigned r = v.u + 0x7fffu + ((v.u >> 16) & 1u);   // RNE
    return (unsigned short)(r >> 16);
}

// ---------- kernel 1 (fused prep): blocks [0,nW) -> Wb row; blocks [nW,..) -> x cast ----------
// UNCHANGED (isolating the GEMM change).
__global__ __launch_bounds__(256) void prep_kernel(
    const float* __restrict__ x,
    const float* __restrict__ W,
    const float* __restrict__ A1, const float* __restrict__ B1,
    const float* __restrict__ A2, const float* __restrict__ B2,
    unsigned short* __restrict__ Xb, unsigned short* __restrict__ Wb,
    int d, int nW, int n8)
{
    int blk = blockIdx.x;
    if (blk < nW) {
        int o  = blk;
        int k0 = threadIdx.x * 8;
        const float4* wrow = (const float4*)(W + (size_t)o * d + k0);
        float4 w0 = wrow[0], w1 = wrow[1];
        float acc[8] = {w0.x, w0.y, w0.z, w0.w, w1.x, w1.y, w1.z, w1.w};
        if (o >= d) {                               // block-uniform branch
            const float* A  = (o < 2 * d) ? A1 : A2;    // [8, d]
            const float* Bm = (o < 2 * d) ? B1 : B2;    // [d, 8]
            int r0 = o - ((o < 2 * d) ? d : 2 * d);
#pragma unroll
            for (int r = 0; r < 8; ++r) {
                float bb = Bm[(size_t)r0 * 8 + r];
                const float4* arow = (const float4*)(A + (size_t)r * d + k0);
                float4 a0 = arow[0], a1 = arow[1];
                acc[0] += bb * a0.x; acc[1] += bb * a0.y;
                acc[2] += bb * a0.z; acc[3] += bb * a0.w;
                acc[4] += bb * a1.x; acc[5] += bb * a1.y;
                acc[6] += bb * a1.z; acc[7] += bb * a1.w;
            }
        }
        ushort8 ov;
#pragma unroll
        for (int c = 0; c < 8; ++c) ov[c] = f2bf(acc[c]);
        ((ushort8*)(Wb + (size_t)o * d))[threadIdx.x] = ov;
    } else {
        int i = (blk - nW) * 256 + threadIdx.x;
        if (i >= n8) return;
        const float4* s = (const float4*)x + (size_t)i * 2;
        float4 a = s[0], c = s[1];
        ushort8 o;
        o[0] = f2bf(a.x); o[1] = f2bf(a.y); o[2] = f2bf(a.z); o[3] = f2bf(a.w);
        o[4] = f2bf(c.x); o[5] = f2bf(c.y); o[6] = f2bf(c.z); o[7] = f2bf(c.w);
        ((ushort8*)Xb)[i] = o;
    }
}

// ---------- kernel 2: 256x256 tile, BK=64, 8-phase counted-vmcnt schedule ----------
// 512 thr = 8 waves (2M x 4N); per-wave 128x64 output = acc[4][2] of 32x32x16 MFMA.
// LDS: 2 buffers x (A 32KB + B 32KB) = 128 KiB. Chunk-XOR swizzle (verified in the
// prior session): LDS slot p of row r holds global k-chunk p^(r&7); read chunk c at
// slot c^(r&7). global_load_lds stays lane-linear; the permutation lives in the
// per-lane GLOBAL source address (rule #21).
//
// Per K-tile group (4 phases, qm-major quadrants):
//  ph1: read a[f01](qm0) + b0(qn0)  | stage B2,B3(v+1)->buf^1 | bar | MFMA acc[0..1][0] | bar
//  ph2: read b1(qn1)                | stage A1,A3(v+1)->buf^1 | bar | MFMA acc[0..1][1] | bar
//  ph3: read a[f01](qm1)            | stage A0,A2(v+2)->buf   | bar | MFMA acc[2..3][0] | bar
//  ph4: (regs held)                 | stage B0,B1(v+2)->buf   | vmcnt(4) | bar | MFMA acc[2..3][1] | bar
// Dest-safety: A-quarters 0,2 of buf are last ds_read at ph1 (frags held in regs for
// ph2) -> dead from ph2; B 64-row calls dead from ph3; buf^1 holds tile v-1, fully
// consumed. vmcnt(4) retires everything older than the 4 ph3/ph4 stages => tile v+1
// fully landed before next group's ph1 reads. vmcnt never drains to 0 in steady state.
constexpr int BM = 256, BN = 256, BK = 64;
constexpr int KK = 2048, NN = 6144;       // fixed by problem shape
constexpr int TT = KK / BK;               // 32 K-tiles

__global__ __launch_bounds__(512, 2) void gemm256_kernel(
    const unsigned short* __restrict__ Xb,
    const unsigned short* __restrict__ Wb,
    const float* __restrict__ bias,
    float* __restrict__ out,
    int M)
{
    __shared__ __align__(16) unsigned short As[2][BM * BK];   // 2 x 32 KiB
    __shared__ __align__(16) unsigned short Bs[2][BN * BK];   // 2 x 32 KiB

    const int tid  = threadIdx.x;
    const int wave = tid >> 6;
    const int lane = tid & 63;
    const int half = lane >> 5;
    const int ln32 = lane & 31;
    const int wrow = wave >> 2;       // 0..1  -> row offset *128
    const int wcol = wave & 3;        // 0..3  -> col offset *64

    // ---- XCD-aware block swizzle (bijective: 768 % 8 == 0) ----
    int nwg = (int)gridDim.x;
    int bid = (int)blockIdx.x;
    int swz = bid;
    if ((nwg & 7) == 0) swz = (bid & 7) * (nwg >> 3) + (bid >> 3);
    const int ntn = NN / BN;          // 24
    const int bm = (swz / ntn) * BM;
    const int bn = (swz % ntn) * BN;

    // ---- staging per-thread constants: call = 64 rows x 8 chunks = 512 lanes ----
    const int rtid = tid >> 3;                     // row-in-call 0..63
    const int ctid = (tid & 7) ^ (rtid & 7);       // swizzled global chunk
    const size_t gA0 = (size_t)(bm + rtid) * KK + ctid * 8;
    const size_t gB0 = (size_t)(bn + rtid) * KK + ctid * 8;
    const int ldsW = wave * 512;                   // shorts: wave covers 8 rows/call

#define STAGE_A(t, j, buf) gload_lds16(Xb + gA0 + (size_t)(j) * 64 * KK + (size_t)(t) * BK, \
                                       &As[(buf)][(j) * 4096 + ldsW])
#define STAGE_B(t, j, buf) gload_lds16(Wb + gB0 + (size_t)(j) * 64 * KK + (size_t)(t) * BK, \
                                       &Bs[(buf)][(j) * 4096 + ldsW])

    // ---- fragment read offsets ----
    const int r7 = ln32 & 7;
    int dofs[4];
#pragma unroll
    for (int s = 0; s < 4; ++s) dofs[s] = ((s * 2 + half) ^ r7) * 8;
    int baseA[2][2];                  // [qm][f]
#pragma unroll
    for (int qm = 0; qm < 2; ++qm)
#pragma unroll
        for (int f = 0; f < 2; ++f)
            baseA[qm][f] = (wrow * 128 + qm * 64 + f * 32 + ln32) * BK;
    int baseB[2];                     // [qn]
#pragma unroll
    for (int qn = 0; qn < 2; ++qn) baseB[qn] = (wcol * 64 + qn * 32 + ln32) * BK;

    f32x16 acc[4][2];
#pragma unroll
    for (int i = 0; i < 4; ++i)
#pragma unroll
        for (int j = 0; j < 2; ++j)
#pragma unroll
            for (int r = 0; r < 16; ++r) acc[i][j][r] = 0.f;

    bf16x8 a[2][4], b0[4], b1[4];

#define LOAD_A(qm) do { _Pragma("unroll") for (int s = 0; s < 4; ++s) {        \
        a[0][s] = *(const bf16x8*)&Aq[baseA[qm][0] + dofs[s]];                 \
        a[1][s] = *(const bf16x8*)&Aq[baseA[qm][1] + dofs[s]]; } } while (0)
#define LOAD_B(qn, BB) do { _Pragma("unroll") for (int s = 0; s < 4; ++s) {    \
        BB[s] = *(const bf16x8*)&Bq[baseB[qn] + dofs[s]]; } } while (0)
#define MFMA_CL(i0, i1, jj, BB) do {                                           \
        __builtin_amdgcn_s_setprio(1);                                         \
        _Pragma("unroll") for (int s = 0; s < 4; ++s) {                        \
            acc[i0][jj] = __builtin_amdgcn_mfma_f32_32x32x16_bf16(a[0][s], BB[s], acc[i0][jj], 0, 0, 0); \
            acc[i1][jj] = __builtin_amdgcn_mfma_f32_32x32x16_bf16(a[1][s], BB[s], acc[i1][jj], 0, 0, 0); \
        }                                                                      \
        __builtin_amdgcn_s_setprio(0); } while (0)
#define BAR() asm volatile("s_barrier" ::: "memory")

#define GROUP(v, SN1, SN2, VMW) do {                                           \
        const int q_ = (v) & 1;                                                \
        const unsigned short* Aq = &As[q_][0];                                 \
        const unsigned short* Bq = &Bs[q_][0];                                 \
        /* ph1 */                                                              \
        LOAD_A(0); LOAD_B(0, b0);                                              \
        if (SN1) { STAGE_B((v) + 1, 2, q_ ^ 1); STAGE_B((v) + 1, 3, q_ ^ 1); } \
        BAR();                                                                 \
        MFMA_CL(0, 1, 0, b0);                                                  \
        BAR();                                                                 \
        /* ph2 */                                                              \
        LOAD_B(1, b1);                                                         \
        if (SN1) { STAGE_A((v) + 1, 1, q_ ^ 1); STAGE_A((v) + 1, 3, q_ ^ 1); } \
        BAR();                                                                 \
        MFMA_CL(0, 1, 1, b1);                                                  \
        BAR();                                                                 \
        /* ph3 */                                                              \
        LOAD_A(1);                                                             \
        if (SN2) { STAGE_A((v) + 2, 0, q_); STAGE_A((v) + 2, 2, q_); }         \
        BAR();                                                                 \
        MFMA_CL(2, 3, 0, b0);                                                  \
        BAR();                                                                 \
        /* ph4 */                                                              \
        if (SN2) { STAGE_B((v) + 2, 0, q_); STAGE_B((v) + 2, 1, q_); }         \
        if ((VMW) == 4)      asm volatile("s_waitcnt vmcnt(4)" ::: "memory");  \
        else if ((VMW) == 0) asm volatile("s_waitcnt vmcnt(0)" ::: "memory");  \
        BAR();                                                                 \
        MFMA_CL(2, 3, 1, b1);                                                  \
        BAR();                                                                 \
    } while (0)

    // ---- prologue: tile0 fully + tile1 {A0,A2,B0,B1}; wait tile0 (4 left in flight) ----
#pragma unroll
    for (int j = 0; j < 4; ++j) STAGE_A(0, j, 0);
#pragma unroll
    for (int j = 0; j < 4; ++j) STAGE_B(0, j, 0);
    STAGE_A(1, 0, 1); STAGE_A(1, 2, 1);
    STAGE_B(1, 0, 1); STAGE_B(1, 1, 1);
    asm volatile("s_waitcnt vmcnt(4)" ::: "memory");
    BAR();

    // ---- main loop: steady groups, then 2 tail groups ----
#pragma unroll 2
    for (int v = 0; v < TT - 2; ++v) GROUP(v, 1, 1, 4);
    GROUP(TT - 2, 1, 0, 0);
    GROUP(TT - 1, 0, 0, -1);

#undef GROUP
#undef BAR
#undef MFMA_CL
#undef LOAD_B
#undef LOAD_A
#undef STAGE_B
#undef STAGE_A

    // ---- epilogue: C/D layout col=lane&31, row=(reg&3)+8*(reg>>2)+4*half (m74/m101) ----
#pragma unroll
    for (int j = 0; j < 2; ++j) {
        int col = bn + wcol * 64 + j * 32 + ln32;
        float bv = bias[col];
#pragma unroll
        for (int i = 0; i < 4; ++i) {
            int rbase = bm + wrow * 128 + i * 32 + 4 * half;
#pragma unroll
            for (int reg = 0; reg < 16; ++reg) {
                int row = rbase + (reg & 3) + 8 * (reg >> 2);
                out[(size_t)row * NN + col] = acc[i][j][reg] + bv;
            }
        }
    }
}

// ---------- launcher ----------
extern "C" void kernel_launch(void* const* d_in, const int* in_sizes, int n_in,
                              void* d_out, int out_size, void* d_ws, size_t ws_size,
                              hipStream_t stream) {
    const float* x  = (const float*)d_in[0];   // [4,2048,2048]
    const float* W  = (const float*)d_in[1];   // [6144,2048]
    const float* b  = (const float*)d_in[2];   // [6144]
    const float* A1 = (const float*)d_in[3];   // [8,2048]
    const float* B1 = (const float*)d_in[4];   // [2048,8]
    const float* A2 = (const float*)d_in[5];   // [8,2048]
    const float* B2 = (const float*)d_in[6];   // [2048,8]
    float* out = (float*)d_out;

    const int d = 2048;
    const int K = d;               // in_features
    const int N = 3 * d;           // 6144 fused rows
    const int M = in_sizes[0] / d; // 8192 = B*S

    unsigned short* Xbf = (unsigned short*)d_ws;              // M*K bf16 = 33.5 MB
    unsigned short* Wbf = Xbf + (size_t)M * K;                // N*K bf16 = 25.2 MB

    // 1) fused: Wb = bf16(W + delta); Xb = bf16(x)   [unchanged this round]
    int n8 = (M * K) / 8;
    int castBlocks = (n8 + 255) / 256;
    prep_kernel<<<N + castBlocks, 256, 0, stream>>>(x, W, A1, B1, A2, B2,
                                                    Xbf, Wbf, d, N, n8);

    // 2) GEMM + bias: 256x256 tiles, 8-phase schedule
    dim3 grid((M / BM) * (N / BN));   // 32*24 = 768
    gemm256_kernel<<<grid, 512, 0, stream>>>(Xbf, Wbf, b, out, M);
}